// Round 2
// baseline (1813.719 us; speedup 1.0000x reference)
//
#include <hip/hip_runtime.h>
#include <hip/hip_cooperative_groups.h>
#include <math.h>

namespace cg = cooperative_groups;

#define VOCAB 50257
#define DD 512
#define H 1024
#define SS 2048
#define LL 16
#define TWO_H 2048
#define XDIM 2576   // D + 2H + L
#define YDIM 1552   // H + L + D
#define NB 1024     // cooperative grid blocks (4 blocks/CU guaranteed)

// ws layout (fp32 offsets)
#define OFF_V      0        // 2048 (zeroed)
#define OFF_CTX    2048     // 2048 (zeroed)
#define OFF_RAW    4096     // 2048
#define OFF_SC     6144     // 2048
#define OFF_X1     8192     // 1024
#define OFF_X2     9216     // 1024
#define OFF_X3     10240    // 1024
#define OFF_G      11264    // 6144 (gi | gh)
#define OFF_Y      17408    // 1552
#define OFF_LOGITS 18960    // 50257
#define OFF_PMAX   69220    // 1024 (per-block logit max)
#define OFF_PSUMP  70244    // 1024 (per-block exp-sum partial)
#define OFF_FBPSUM 71268    // 128  (fallback path)
#define OFF_GMAXU  71396    // 1    (fallback path)

__device__ __forceinline__ float bf2f(unsigned short s) {
  union { unsigned u; float f; } t; t.u = ((unsigned)s) << 16; return t.f;
}
__device__ __forceinline__ float bflo(unsigned w) {
  union { unsigned u; float f; } t; t.u = w << 16; return t.f;
}
__device__ __forceinline__ float bfhi(unsigned w) {
  union { unsigned u; float f; } t; t.u = w & 0xffff0000u; return t.f;
}
__device__ __forceinline__ unsigned short f2bf(float f) {
  union { float f; unsigned u; } t; t.f = f;
  unsigned r = (t.u + 0x7FFFu + ((t.u >> 16) & 1u)) >> 16;
  return (unsigned short)r;
}
template<bool BF>
__device__ __forceinline__ float ldv(const void* p, size_t i) {
  if (BF) return bf2f(((const unsigned short*)p)[i]);
  else    return ((const float*)p)[i];
}
template<bool BF>
__device__ __forceinline__ void stv(void* p, size_t i, float v) {
  if (BF) ((unsigned short*)p)[i] = f2bf(v);
  else    ((float*)p)[i] = v;
}
__device__ __forceinline__ unsigned enc_f(float f) {
  unsigned u = __float_as_uint(f);
  return (u & 0x80000000u) ? ~u : (u | 0x80000000u);
}
__device__ __forceinline__ float dec_f(unsigned u) {
  unsigned v = (u & 0x80000000u) ? (u & 0x7FFFFFFFu) : ~u;
  return __uint_as_float(v);
}

__device__ __forceinline__ float wave_reduce(float acc) {
  #pragma unroll
  for (int off = 32; off; off >>= 1) acc += __shfl_down(acc, off, 64);
  return acc;
}
// deterministic all-lane butterfly sum
__device__ __forceinline__ float wave_allreduce(float acc) {
  #pragma unroll
  for (int off = 32; off; off >>= 1) acc += __shfl_xor(acc, off, 64);
  return acc;
}
__device__ __forceinline__ float wave_allreduce_max(float m) {
  #pragma unroll
  for (int off = 32; off; off >>= 1) m = fmaxf(m, __shfl_xor(m, off, 64));
  return m;
}

// ======================= cooperative mega kernel =======================
template<bool BF>
__global__ __launch_bounds__(256, 4)
void mega_kernel(const int* __restrict__ token,
                 const void* __restrict__ hidden,
                 const void* __restrict__ enc,
                 const void* __restrict__ nlg,
                 const void* __restrict__ embedding,
                 const void* __restrict__ attn_W,
                 const void* __restrict__ comb_W, const void* __restrict__ comb_b,
                 const void* __restrict__ fc1_W, const void* __restrict__ fc1_b,
                 const void* __restrict__ fc2_W, const void* __restrict__ fc2_b,
                 const void* __restrict__ gru_Wih, const void* __restrict__ gru_Whh,
                 const void* __restrict__ gru_bih, const void* __restrict__ gru_bhh,
                 const void* __restrict__ out_W, const void* __restrict__ out_b,
                 float* __restrict__ ws, void* __restrict__ d_out) {
  cg::grid_group grid = cg::this_grid();
  const int bid = blockIdx.x, t = threadIdx.x;
  const int wave = t >> 6, lane = t & 63;
  const int gw = bid * 4 + wave;          // global wave id: 0..4095
  const int gid = bid * 256 + t;          // global thread id: 0..262143

  __shared__ float ys[YDIM];
  __shared__ float sred[256];
  __shared__ float hs[32];
  __shared__ float scs[64];

  // ---- phase 0: zero v/ctx, fill y tail [nlg, emb] ----
  if (gid < 4096) ws[OFF_V + gid] = 0.f;
  {
    int j = gid - 4352;
    if (j >= 0 && j < (LL + DD)) {
      float v = (j < LL) ? ldv<BF>(nlg, j)
                         : ldv<BF>(embedding, (size_t)token[0] * DD + (j - LL));
      ws[OFF_Y + H + j] = v;
    }
  }
  grid.sync();

  // ---- phase 1: v[k] = sum_j attn_W[j][k] * h[j]  (blocks 0..255) ----
  if (bid < 256) {
    int kblk = bid & 7, jblk = bid >> 3;
    int j0 = jblk * 32;
    if (t < 32) hs[t] = ldv<BF>(hidden, j0 + t);
    __syncthreads();
    int k = kblk * 256 + t;
    float acc = 0.f;
    #pragma unroll 8
    for (int jj = 0; jj < 32; ++jj)
      acc += ldv<BF>(attn_W, (size_t)(j0 + jj) * TWO_H + k) * hs[jj];
    atomicAdd(&ws[OFF_V + k], acc);
  }
  grid.sync();

  // ---- phase 2: raw[s] = enc[s] . v  (one row per wave, rows 0..2047) ----
  if (gw < SS) {
    const float* vv = ws + OFF_V;
    float acc = 0.f;
    if (BF) {
      const uint4* Er = (const uint4*)((const unsigned short*)enc + (size_t)gw * TWO_H);
      #pragma unroll 4
      for (int c = lane; c < (TWO_H >> 3); c += 64) {
        uint4 u = Er[c]; const float* xp = vv + (c << 3);
        acc += bflo(u.x)*xp[0] + bfhi(u.x)*xp[1] + bflo(u.y)*xp[2] + bfhi(u.y)*xp[3]
             + bflo(u.z)*xp[4] + bfhi(u.z)*xp[5] + bflo(u.w)*xp[6] + bfhi(u.w)*xp[7];
      }
    } else {
      const float4* Er = (const float4*)((const float*)enc + (size_t)gw * TWO_H);
      #pragma unroll 4
      for (int c = lane; c < (TWO_H >> 2); c += 64) {
        float4 u = Er[c]; const float* xp = vv + (c << 2);
        acc += u.x*xp[0] + u.y*xp[1] + u.z*xp[2] + u.w*xp[3];
      }
    }
    acc = wave_reduce(acc);
    if (lane == 0) ws[OFF_RAW + gw] = acc;   // attn_b.h constant across s: cancels
  }
  grid.sync();

  // ---- phase 3: softmax over 2048 (block 0 only) + attn-weight output ----
  if (bid == 0) {
    float m = -3.4e38f;
    for (int i = t; i < SS; i += 256) m = fmaxf(m, ws[OFF_RAW + i]);
    sred[t] = m; __syncthreads();
    for (int s = 128; s; s >>= 1) { if (t < s) sred[t] = fmaxf(sred[t], sred[t + s]); __syncthreads(); }
    float gm = sred[0]; __syncthreads();
    float sum = 0.f;
    for (int i = t; i < SS; i += 256) { float e = expf(ws[OFF_RAW + i] - gm); ws[OFF_SC + i] = e; sum += e; }
    sred[t] = sum; __syncthreads();
    for (int s = 128; s; s >>= 1) { if (t < s) sred[t] += sred[t + s]; __syncthreads(); }
    float inv = 1.f / sred[0];
    for (int i = t; i < SS; i += 256) {
      float sc = ws[OFF_SC + i] * inv;
      ws[OFF_SC + i] = sc;
      stv<BF>(d_out, (size_t)(VOCAB + H) + i, sc);
    }
  }
  grid.sync();

  // ---- phase 4: ctx[k] = sum_s sc[s] * enc[s][k]  (blocks 0..255) ----
  if (bid < 256) {
    int kblk = bid & 7, sblk = bid >> 3;
    int s0 = sblk * 64;
    if (t < 64) scs[t] = ws[OFF_SC + s0 + t];
    __syncthreads();
    int k = kblk * 256 + t;
    float acc = 0.f;
    #pragma unroll 8
    for (int s = 0; s < 64; ++s)
      acc += scs[s] * ldv<BF>(enc, (size_t)(s0 + s) * TWO_H + k);
    atomicAdd(&ws[OFF_CTX + k], acc);
  }
  grid.sync();

  // ---- phase 5: comb (row = bid), virtual x = [emb | ctx | nlg] ----
  {
    int row = bid;
    size_t ebase = (size_t)token[0] * DD;
    float acc = 0.f;
    for (int c4 = t; c4 < (XDIM >> 2); c4 += 256) {
      int c = c4 << 2;
      float x0, x1, x2, x3v;
      if (c < DD) {
        x0 = ldv<BF>(embedding, ebase + c);     x1 = ldv<BF>(embedding, ebase + c + 1);
        x2 = ldv<BF>(embedding, ebase + c + 2); x3v = ldv<BF>(embedding, ebase + c + 3);
      } else if (c < DD + TWO_H) {
        const float* cp = ws + OFF_CTX + (c - DD);
        x0 = cp[0]; x1 = cp[1]; x2 = cp[2]; x3v = cp[3];
      } else {
        int b = c - DD - TWO_H;
        x0 = ldv<BF>(nlg, b);     x1 = ldv<BF>(nlg, b + 1);
        x2 = ldv<BF>(nlg, b + 2); x3v = ldv<BF>(nlg, b + 3);
      }
      if (BF) {
        uint2 u = ((const uint2*)((const unsigned short*)comb_W + (size_t)row * XDIM))[c4];
        acc += bflo(u.x)*x0 + bfhi(u.x)*x1 + bflo(u.y)*x2 + bfhi(u.y)*x3v;
      } else {
        float4 u = ((const float4*)((const float*)comb_W + (size_t)row * XDIM))[c4];
        acc += u.x*x0 + u.y*x1 + u.z*x2 + u.w*x3v;
      }
    }
    acc = wave_reduce(acc);
    if (lane == 0) sred[wave] = acc;
    __syncthreads();
    if (t == 0)
      ws[OFF_X1 + row] = fmaxf(sred[0] + sred[1] + sred[2] + sred[3] + ldv<BF>(comb_b, row), 0.f);
  }
  grid.sync();

  // ---- phase 6: fc1 (row = bid, K=1024, one chunk of 4 per thread) ----
  {
    int row = bid;
    const float* xp = ws + OFF_X1 + t * 4;
    float acc;
    if (BF) {
      uint2 u = ((const uint2*)((const unsigned short*)fc1_W + (size_t)row * H))[t];
      acc = bflo(u.x)*xp[0] + bfhi(u.x)*xp[1] + bflo(u.y)*xp[2] + bfhi(u.y)*xp[3];
    } else {
      float4 u = ((const float4*)((const float*)fc1_W + (size_t)row * H))[t];
      acc = u.x*xp[0] + u.y*xp[1] + u.z*xp[2] + u.w*xp[3];
    }
    acc = wave_reduce(acc);
    if (lane == 0) sred[wave] = acc;
    __syncthreads();
    if (t == 0)
      ws[OFF_X2 + row] = fmaxf(sred[0] + sred[1] + sred[2] + sred[3] + ldv<BF>(fc1_b, row), 0.f);
  }
  grid.sync();

  // ---- phase 7: fc2 ----
  {
    int row = bid;
    const float* xp = ws + OFF_X2 + t * 4;
    float acc;
    if (BF) {
      uint2 u = ((const uint2*)((const unsigned short*)fc2_W + (size_t)row * H))[t];
      acc = bflo(u.x)*xp[0] + bfhi(u.x)*xp[1] + bflo(u.y)*xp[2] + bfhi(u.y)*xp[3];
    } else {
      float4 u = ((const float4*)((const float*)fc2_W + (size_t)row * H))[t];
      acc = u.x*xp[0] + u.y*xp[1] + u.z*xp[2] + u.w*xp[3];
    }
    acc = wave_reduce(acc);
    if (lane == 0) sred[wave] = acc;
    __syncthreads();
    if (t == 0)
      ws[OFF_X3 + row] = fmaxf(sred[0] + sred[1] + sred[2] + sred[3] + ldv<BF>(fc2_b, row), 0.f);
  }
  grid.sync();

  // ---- phase 8: GRU matvecs, 6144 rows (one row per wave, 2 passes) ----
  for (int rr = gw; rr < 6 * H; rr += 4096) {
    bool ih = rr < 3 * H;
    int r = ih ? rr : rr - 3 * H;
    const void* W = ih ? gru_Wih : gru_Whh;
    float acc = 0.f;
    #pragma unroll
    for (int p = 0; p < 4; ++p) {
      int c4 = lane + p * 64;            // chunk of 4, 256 chunks total
      float x0, x1, x2, x3v;
      if (ih) {
        const float* xp = ws + OFF_X3 + c4 * 4;
        x0 = xp[0]; x1 = xp[1]; x2 = xp[2]; x3v = xp[3];
      } else {
        x0 = ldv<BF>(hidden, c4 * 4);     x1 = ldv<BF>(hidden, c4 * 4 + 1);
        x2 = ldv<BF>(hidden, c4 * 4 + 2); x3v = ldv<BF>(hidden, c4 * 4 + 3);
      }
      if (BF) {
        uint2 u = ((const uint2*)((const unsigned short*)W + (size_t)r * H))[c4];
        acc += bflo(u.x)*x0 + bfhi(u.x)*x1 + bflo(u.y)*x2 + bfhi(u.y)*x3v;
      } else {
        float4 u = ((const float4*)((const float*)W + (size_t)r * H))[c4];
        acc += u.x*x0 + u.y*x1 + u.z*x2 + u.w*x3v;
      }
    }
    acc = wave_reduce(acc);
    if (lane == 0) ws[OFF_G + rr] = acc + ldv<BF>(ih ? gru_bih : gru_bhh, r);
  }
  grid.sync();

  // ---- phase 9: gates -> h_new into y[0..H) and d_out ----
  if (gid < H) {
    const float* gi = ws + OFF_G;
    const float* gh = ws + OFF_G + 3 * H;
    int i = gid;
    float r = 1.f / (1.f + expf(-(gi[i] + gh[i])));
    float z = 1.f / (1.f + expf(-(gi[H + i] + gh[H + i])));
    float n = tanhf(gi[2 * H + i] + r * gh[2 * H + i]);
    float hp = ldv<BF>(hidden, i);
    float hn = (1.f - z) * n + z * hp;
    ws[OFF_Y + i] = hn;
    stv<BF>(d_out, (size_t)VOCAB + i, hn);
  }
  grid.sync();

  // ---- phase 10: logits (grid-stride rows per wave) + per-block max ----
  for (int i = t; i < YDIM; i += 256) ys[i] = ws[OFF_Y + i];
  __syncthreads();
  {
    float wmax = -3.4e38f;
    for (int row = gw; row < VOCAB; row += 4096) {
      float acc = 0.f;
      if (BF) {
        const unsigned short* Wr = (const unsigned short*)out_W + (size_t)row * YDIM;
        for (int c = lane; c < (YDIM >> 3); c += 64) {       // 194 chunks of 8
          uint4 u = ((const uint4*)Wr)[c];
          const float* xp = ys + (c << 3);
          acc += bflo(u.x)*xp[0] + bfhi(u.x)*xp[1] + bflo(u.y)*xp[2] + bfhi(u.y)*xp[3]
               + bflo(u.z)*xp[4] + bfhi(u.z)*xp[5] + bflo(u.w)*xp[6] + bfhi(u.w)*xp[7];
        }
      } else {
        const float* Wr = (const float*)out_W + (size_t)row * YDIM;
        for (int c = lane; c < (YDIM >> 2); c += 64) {       // 388 chunks of 4
          float4 u = ((const float4*)Wr)[c];
          const float* xp = ys + (c << 2);
          acc += u.x*xp[0] + u.y*xp[1] + u.z*xp[2] + u.w*xp[3];
        }
      }
      acc = wave_reduce(acc);
      if (lane == 0) {
        float lv = acc + ldv<BF>(out_b, row);
        ws[OFF_LOGITS + row] = lv;
        wmax = fmaxf(wmax, lv);
      }
    }
    if (lane == 0) sred[wave] = wmax;
    __syncthreads();
    if (t == 0)
      ws[OFF_PMAX + bid] = fmaxf(fmaxf(sred[0], sred[1]), fmaxf(sred[2], sred[3]));
  }
  grid.sync();

  // ---- phase 11: gm (each block redundantly, deterministic) + psum partial ----
  float gm_save;
  {
    float m = fmaxf(fmaxf(ws[OFF_PMAX + t], ws[OFF_PMAX + t + 256]),
                    fmaxf(ws[OFF_PMAX + t + 512], ws[OFF_PMAX + t + 768]));
    m = wave_allreduce_max(m);
    if (lane == 0) sred[wave] = m;
    __syncthreads();
    float gm = fmaxf(fmaxf(sred[0], sred[1]), fmaxf(sred[2], sred[3]));
    __syncthreads();
    gm_save = gm;
    float s = (gid < VOCAB) ? expf(ws[OFF_LOGITS + gid] - gm) : 0.f;
    s = wave_allreduce(s);
    if (lane == 0) sred[wave] = s;
    __syncthreads();
    if (t == 0) ws[OFF_PSUMP + bid] = sred[0] + sred[1] + sred[2] + sred[3];
  }
  grid.sync();

  // ---- phase 12: total sum (each block, fixed order) + writeout ----
  {
    float s = ws[OFF_PSUMP + t] + ws[OFF_PSUMP + t + 256]
            + ws[OFF_PSUMP + t + 512] + ws[OFF_PSUMP + t + 768];
    s = wave_allreduce(s);
    if (lane == 0) sred[wave] = s;
    __syncthreads();
    float tot = sred[0] + sred[1] + sred[2] + sred[3];
    float lz = gm_save + logf(tot);
    if (gid < VOCAB) stv<BF>(d_out, gid, ws[OFF_LOGITS + gid] - lz);
  }
}

// ======================= fallback (round-1) kernels =======================
__device__ __forceinline__ float block_reduce_256(float acc) {
  #pragma unroll
  for (int off = 32; off; off >>= 1) acc += __shfl_down(acc, off, 64);
  __shared__ float r4[4];
  if ((threadIdx.x & 63) == 0) r4[threadIdx.x >> 6] = acc;
  __syncthreads();
  return r4[0] + r4[1] + r4[2] + r4[3];
}

template<bool BF>
__global__ __launch_bounds__(256)
void init_kernel(const void* __restrict__ nlg, const void* __restrict__ embedding,
                 const int* __restrict__ token, float* __restrict__ ws) {
  int i = blockIdx.x * 256 + threadIdx.x;
  if (i < 4096) ws[OFF_V + i] = 0.f;
  if (i == 4100) *(unsigned*)(ws + OFF_GMAXU) = 0u;
  int j = i - 4352;
  if (j >= 0 && j < (YDIM - H)) {
    float v;
    if (j < LL) v = ldv<BF>(nlg, j);
    else        v = ldv<BF>(embedding, (size_t)token[0] * DD + (j - LL));
    ws[OFF_Y + H + j] = v;
  }
}

template<bool BF>
__global__ __launch_bounds__(256)
void attn_v_kernel(const void* __restrict__ W, const void* __restrict__ hidden,
                   float* __restrict__ v) {
  __shared__ float hs[32];
  int j0 = blockIdx.y * 32;
  if (threadIdx.x < 32) hs[threadIdx.x] = ldv<BF>(hidden, j0 + threadIdx.x);
  __syncthreads();
  int k = blockIdx.x * 256 + threadIdx.x;
  float acc = 0.f;
  #pragma unroll 8
  for (int j = 0; j < 32; ++j)
    acc += ldv<BF>(W, (size_t)(j0 + j) * TWO_H + k) * hs[j];
  atomicAdd(&v[k], acc);
}

template<bool BF, bool RELU>
__global__ __launch_bounds__(256)
void matvec_kernel(const void* __restrict__ W, const void* __restrict__ bias,
                   const float* __restrict__ x, float* __restrict__ out, int K) {
  int row = blockIdx.x, t = threadIdx.x;
  float acc = 0.f;
  int nc = K >> 2;
  if (BF) {
    const uint2* Wr = (const uint2*)((const unsigned short*)W + (size_t)row * K);
    for (int c = t; c < nc; c += 256) {
      uint2 u = Wr[c]; const float* xp = x + c * 4;
      acc += bflo(u.x)*xp[0] + bfhi(u.x)*xp[1] + bflo(u.y)*xp[2] + bfhi(u.y)*xp[3];
    }
  } else {
    const float4* Wr = (const float4*)((const float*)W + (size_t)row * K);
    for (int c = t; c < nc; c += 256) {
      float4 u = Wr[c]; const float* xp = x + c * 4;
      acc += u.x*xp[0] + u.y*xp[1] + u.z*xp[2] + u.w*xp[3];
    }
  }
  float s = block_reduce_256(acc);
  if (t == 0) {
    if (bias) s += ldv<BF>(bias, row);
    if (RELU) s = fmaxf(s, 0.f);
    out[row] = s;
  }
}

template<bool BF>
__global__ __launch_bounds__(256)
void softmax2048_kernel(const float* __restrict__ raw, float* __restrict__ scores,
                        void* __restrict__ d_out) {
  __shared__ float red[256];
  int t = threadIdx.x;
  float m = -3.4e38f;
  for (int i = t; i < SS; i += 256) m = fmaxf(m, raw[i]);
  red[t] = m; __syncthreads();
  for (int s = 128; s; s >>= 1) { if (t < s) red[t] = fmaxf(red[t], red[t + s]); __syncthreads(); }
  float gm = red[0]; __syncthreads();
  float sum = 0.f;
  for (int i = t; i < SS; i += 256) { float e = expf(raw[i] - gm); scores[i] = e; sum += e; }
  red[t] = sum; __syncthreads();
  for (int s = 128; s; s >>= 1) { if (t < s) red[t] += red[t + s]; __syncthreads(); }
  float inv = 1.f / red[0];
  for (int i = t; i < SS; i += 256) {
    float sc = scores[i] * inv;
    scores[i] = sc;
    stv<BF>(d_out, (size_t)(VOCAB + H) + i, sc);
  }
}

template<bool BF>
__global__ __launch_bounds__(256)
void context_kernel(const void* __restrict__ enc, const float* __restrict__ scores,
                    float* __restrict__ ctx) {
  __shared__ float ss[64];
  int s0 = blockIdx.y * 64;
  if (threadIdx.x < 64) ss[threadIdx.x] = scores[s0 + threadIdx.x];
  __syncthreads();
  int k = blockIdx.x * 256 + threadIdx.x;
  float acc = 0.f;
  #pragma unroll 8
  for (int s = 0; s < 64; ++s)
    acc += ss[s] * ldv<BF>(enc, (size_t)(s0 + s) * TWO_H + k);
  atomicAdd(&ctx[k], acc);
}

template<bool BF>
__global__ __launch_bounds__(256)
void comb_kernel(const void* __restrict__ W, const void* __restrict__ bias,
                 const void* __restrict__ embedding, const float* __restrict__ ctx,
                 const void* __restrict__ nlg, const int* __restrict__ token,
                 float* __restrict__ out) {
  int row = blockIdx.x, t = threadIdx.x;
  size_t ebase = (size_t)token[0] * DD;
  float acc = 0.f;
  for (int c4 = t; c4 < (XDIM >> 2); c4 += 256) {
    int c = c4 << 2;
    float x0, x1, x2, x3v;
    if (c < DD) {
      x0 = ldv<BF>(embedding, ebase + c);     x1 = ldv<BF>(embedding, ebase + c + 1);
      x2 = ldv<BF>(embedding, ebase + c + 2); x3v = ldv<BF>(embedding, ebase + c + 3);
    } else if (c < DD + TWO_H) {
      const float* cp = ctx + (c - DD);
      x0 = cp[0]; x1 = cp[1]; x2 = cp[2]; x3v = cp[3];
    } else {
      int b = c - DD - TWO_H;
      x0 = ldv<BF>(nlg, b);     x1 = ldv<BF>(nlg, b + 1);
      x2 = ldv<BF>(nlg, b + 2); x3v = ldv<BF>(nlg, b + 3);
    }
    if (BF) {
      uint2 u = ((const uint2*)((const unsigned short*)W + (size_t)row * XDIM))[c4];
      acc += bflo(u.x)*x0 + bfhi(u.x)*x1 + bflo(u.y)*x2 + bfhi(u.y)*x3v;
    } else {
      float4 u = ((const float4*)((const float*)W + (size_t)row * XDIM))[c4];
      acc += u.x*x0 + u.y*x1 + u.z*x2 + u.w*x3v;
    }
  }
  float s = block_reduce_256(acc);
  if (t == 0) out[row] = fmaxf(s + ldv<BF>(bias, row), 0.f);
}

template<bool BF>
__global__ __launch_bounds__(256)
void gru2_kernel(const void* __restrict__ Wih, const void* __restrict__ Whh,
                 const void* __restrict__ bih, const void* __restrict__ bhh,
                 const float* __restrict__ x3, const void* __restrict__ hidden,
                 float* __restrict__ g) {
  int row = blockIdx.x, t = threadIdx.x;
  bool ih = row < 3 * H;
  int r = ih ? row : row - 3 * H;
  const void* W = ih ? Wih : Whh;
  float x0, x1, x2, x3v;
  if (ih) {
    const float* xp = x3 + t * 4;
    x0 = xp[0]; x1 = xp[1]; x2 = xp[2]; x3v = xp[3];
  } else {
    x0 = ldv<BF>(hidden, 4 * t);     x1 = ldv<BF>(hidden, 4 * t + 1);
    x2 = ldv<BF>(hidden, 4 * t + 2); x3v = ldv<BF>(hidden, 4 * t + 3);
  }
  float acc;
  if (BF) {
    uint2 u = ((const uint2*)((const unsigned short*)W + (size_t)r * H))[t];
    acc = bflo(u.x)*x0 + bfhi(u.x)*x1 + bflo(u.y)*x2 + bfhi(u.y)*x3v;
  } else {
    float4 u = ((const float4*)((const float*)W + (size_t)r * H))[t];
    acc = u.x*x0 + u.y*x1 + u.z*x2 + u.w*x3v;
  }
  float s = block_reduce_256(acc);
  if (t == 0) g[row] = s + ldv<BF>(ih ? bih : bhh, r);
}

template<bool BF>
__global__ __launch_bounds__(256)
void gates_kernel(const float* __restrict__ g, const void* __restrict__ hidden,
                  float* __restrict__ y, void* __restrict__ d_out) {
  int i = blockIdx.x * 256 + threadIdx.x;
  if (i >= H) return;
  const float* gi = g;
  const float* gh = g + 3 * H;
  float r = 1.f / (1.f + expf(-(gi[i] + gh[i])));
  float z = 1.f / (1.f + expf(-(gi[H + i] + gh[H + i])));
  float n = tanhf(gi[2 * H + i] + r * gh[2 * H + i]);
  float hp = ldv<BF>(hidden, i);
  float hn = (1.f - z) * n + z * hp;
  y[i] = hn;
  stv<BF>(d_out, (size_t)VOCAB + i, hn);
}

template<bool BF>
__global__ __launch_bounds__(512)
void logits_kernel(const void* __restrict__ W, const void* __restrict__ bias,
                   const float* __restrict__ y, float* __restrict__ logits,
                   unsigned* __restrict__ gmaxU) {
  __shared__ float ysl[YDIM];
  for (int i = threadIdx.x; i < YDIM; i += 512) ysl[i] = y[i];
  __syncthreads();
  int wave = threadIdx.x >> 6, lane = threadIdx.x & 63;
  int row = blockIdx.x * 8 + wave;
  float val = -3.4e38f;
  if (row < VOCAB) {
    float acc = 0.f;
    if (BF) {
      const unsigned short* Wr = (const unsigned short*)W + (size_t)row * YDIM;
      for (int c = lane; c < (YDIM >> 3); c += 64) {
        uint4 u = ((const uint4*)Wr)[c];
        const float* xp = ysl + (c << 3);
        acc += bflo(u.x)*xp[0] + bfhi(u.x)*xp[1] + bflo(u.y)*xp[2] + bfhi(u.y)*xp[3]
             + bflo(u.z)*xp[4] + bfhi(u.z)*xp[5] + bflo(u.w)*xp[6] + bfhi(u.w)*xp[7];
      }
    } else {
      const float* Wr = (const float*)W + (size_t)row * YDIM;
      for (int c = lane; c < (YDIM >> 2); c += 64) {
        float4 u = ((const float4*)Wr)[c];
        const float* xp = ysl + (c << 2);
        acc += u.x*xp[0] + u.y*xp[1] + u.z*xp[2] + u.w*xp[3];
      }
    }
    #pragma unroll
    for (int off = 32; off; off >>= 1) acc += __shfl_down(acc, off, 64);
    if (lane == 0) {
      float lv = acc + ldv<BF>(bias, row);
      logits[row] = lv;
      val = lv;
    }
  }
  __shared__ float wmax[8];
  if (lane == 0) wmax[wave] = val;
  __syncthreads();
  if (threadIdx.x == 0) {
    float m = wmax[0];
    #pragma unroll
    for (int k = 1; k < 8; ++k) m = fmaxf(m, wmax[k]);
    atomicMax(gmaxU, enc_f(m));
  }
}

__global__ __launch_bounds__(256)
void psum_kernel(const float* __restrict__ logits, const unsigned* __restrict__ gmaxU,
                 float* __restrict__ psum) {
  float gm = dec_f(*gmaxU);
  float s = 0.f;
  for (int i = blockIdx.x * 256 + threadIdx.x; i < VOCAB; i += 128 * 256)
    s += expf(logits[i] - gm);
  float tot = block_reduce_256(s);
  if (threadIdx.x == 0) psum[blockIdx.x] = tot;
}

template<bool BF>
__global__ __launch_bounds__(256)
void writeout_kernel(const float* __restrict__ logits, const float* __restrict__ psum,
                     const unsigned* __restrict__ gmaxU, void* __restrict__ out) {
  int t = threadIdx.x;
  float s = (t < 128) ? psum[t] : 0.f;
  float tot = block_reduce_256(s);
  __shared__ float lz;
  if (t == 0) lz = dec_f(*gmaxU) + logf(tot);
  __syncthreads();
  int i = blockIdx.x * 256 + t;
  if (i < VOCAB) stv<BF>(out, i, logits[i] - lz);
}

template<bool BF>
static void launch_fallback(void* const* d_in, void* d_out, float* ws, hipStream_t stream) {
  const int* token      = (const int*)d_in[0];
  const void* hidden    = d_in[1];
  const void* enc       = d_in[2];
  const void* nlg       = d_in[3];
  const void* embedding = d_in[4];
  const void* attn_W    = d_in[5];
  const void* comb_W    = d_in[7];
  const void* comb_b    = d_in[8];
  const void* fc1_W     = d_in[9];
  const void* fc1_b     = d_in[10];
  const void* fc2_W     = d_in[11];
  const void* fc2_b     = d_in[12];
  const void* gru_Wih   = d_in[13];
  const void* gru_Whh   = d_in[14];
  const void* gru_bih   = d_in[15];
  const void* gru_bhh   = d_in[16];
  const void* out_W     = d_in[17];
  const void* out_b     = d_in[18];
  unsigned* gmaxU = (unsigned*)(ws + OFF_GMAXU);

  init_kernel<BF><<<20, 256, 0, stream>>>(nlg, embedding, token, ws);
  attn_v_kernel<BF><<<dim3(8, 32), 256, 0, stream>>>(attn_W, hidden, ws + OFF_V);
  matvec_kernel<BF, false><<<SS, 256, 0, stream>>>(enc, nullptr, ws + OFF_V, ws + OFF_RAW, TWO_H);
  softmax2048_kernel<BF><<<1, 256, 0, stream>>>(ws + OFF_RAW, ws + OFF_SC, d_out);
  context_kernel<BF><<<dim3(8, 32), 256, 0, stream>>>(enc, ws + OFF_SC, ws + OFF_CTX);
  comb_kernel<BF><<<H, 256, 0, stream>>>(comb_W, comb_b, embedding, ws + OFF_CTX, nlg, token, ws + OFF_X1);
  matvec_kernel<BF, true><<<H, 256, 0, stream>>>(fc1_W, fc1_b, ws + OFF_X1, ws + OFF_X2, H);
  matvec_kernel<BF, true><<<H, 256, 0, stream>>>(fc2_W, fc2_b, ws + OFF_X2, ws + OFF_X3, H);
  gru2_kernel<BF><<<6 * H, 256, 0, stream>>>(gru_Wih, gru_Whh, gru_bih, gru_bhh,
                                             ws + OFF_X3, hidden, ws + OFF_G);
  gates_kernel<BF><<<4, 256, 0, stream>>>(ws + OFF_G, hidden, ws + OFF_Y, d_out);
  logits_kernel<BF><<<(VOCAB + 7) / 8, 512, 0, stream>>>(out_W, out_b, ws + OFF_Y,
                                                         ws + OFF_LOGITS, gmaxU);
  psum_kernel<<<128, 256, 0, stream>>>(ws + OFF_LOGITS, gmaxU, ws + OFF_FBPSUM);
  writeout_kernel<BF><<<(VOCAB + 255) / 256, 256, 0, stream>>>(ws + OFF_LOGITS, ws + OFF_FBPSUM,
                                                               gmaxU, d_out);
}

template<bool BF>
static void launch_mega(void* const* d_in, void* d_out, float* ws, hipStream_t stream) {
  const int* token      = (const int*)d_in[0];
  const void* hidden    = d_in[1];
  const void* enc       = d_in[2];
  const void* nlg       = d_in[3];
  const void* embedding = d_in[4];
  const void* attn_W    = d_in[5];
  const void* comb_W    = d_in[7];
  const void* comb_b    = d_in[8];
  const void* fc1_W     = d_in[9];
  const void* fc1_b     = d_in[10];
  const void* fc2_W     = d_in[11];
  const void* fc2_b     = d_in[12];
  const void* gru_Wih   = d_in[13];
  const void* gru_Whh   = d_in[14];
  const void* gru_bih   = d_in[15];
  const void* gru_bhh   = d_in[16];
  const void* out_W     = d_in[17];
  const void* out_b     = d_in[18];
  void* outp = d_out;
  float* wsp = ws;

  void* args[] = { &token, &hidden, &enc, &nlg, &embedding, &attn_W,
                   &comb_W, &comb_b, &fc1_W, &fc1_b, &fc2_W, &fc2_b,
                   &gru_Wih, &gru_Whh, &gru_bih, &gru_bhh, &out_W, &out_b,
                   &wsp, &outp };
  hipError_t e = hipLaunchCooperativeKernel((const void*)mega_kernel<BF>,
                                            dim3(NB), dim3(256), args, 0, stream);
  if (e != hipSuccess) launch_fallback<BF>(d_in, d_out, ws, stream);
}

extern "C" void kernel_launch(void* const* d_in, const int* in_sizes, int n_in,
                              void* d_out, int out_size, void* d_ws, size_t ws_size,
                              hipStream_t stream) {
  (void)n_in; (void)out_size; (void)ws_size;
  // Host-side dtype dispatch: embedding byte size uniquely identifies the dtype.
  bool bf = (in_sizes && in_sizes[4] == VOCAB * DD * 2);
  float* ws = (float*)d_ws;
  if (bf) launch_mega<true >(d_in, d_out, ws, stream);
  else    launch_mega<false>(d_in, d_out, ws, stream);
}